// Round 1
// baseline (1573.584 us; speedup 1.0000x reference)
//
#include <hip/hip_runtime.h>
#include <hip/hip_bf16.h>

// ---------------- model constants ----------------
static constexpr int SEQ   = 2048;
static constexpr int DM    = 2048;
static constexpr int NHEAD = 16;
static constexpr int NKVH  = 8;
static constexpr int HDIM  = 128;
static constexpr int FFN   = 6144;
static constexpr int NLAYER = 2;
static constexpr float EPSV = 1e-6f;
static constexpr int CHUNK = 4;   // q-heads per attention chunk

typedef __attribute__((ext_vector_type(8))) short bf16x8;
typedef __attribute__((ext_vector_type(4))) float f32x4;

__device__ __forceinline__ float wave_sum(float v) {
#pragma unroll
    for (int o = 32; o > 0; o >>= 1) v += __shfl_xor(v, o);
    return v;
}
__device__ __forceinline__ float wave_max(float v) {
#pragma unroll
    for (int o = 32; o > 0; o >>= 1) v = fmaxf(v, __shfl_xor(v, o));
    return v;
}

// ---------------- embedding gather ----------------
__global__ void embed_k(const int* __restrict__ ids, const float* __restrict__ emb,
                        float* __restrict__ h) {
    const int s = blockIdx.x;
    const long src = (long)ids[s] * DM;
    for (int t = threadIdx.x; t < DM; t += 256)
        h[(long)s * DM + t] = emb[src + t];
}

// ---------------- RMSNorm (f32 in -> bf16 out) ----------------
__global__ void rmsnorm_k(const float* __restrict__ in, const float* __restrict__ g,
                          __hip_bfloat16* __restrict__ out) {
    const int row = blockIdx.x;
    const float* r = in + (long)row * DM;
    const int tid = threadIdx.x;
    float v[8];
    float ss = 0.f;
#pragma unroll
    for (int t = 0; t < 8; ++t) { v[t] = r[tid + t * 256]; ss += v[t] * v[t]; }
    ss = wave_sum(ss);
    __shared__ float sp[4];
    if ((tid & 63) == 0) sp[tid >> 6] = ss;
    __syncthreads();
    ss = sp[0] + sp[1] + sp[2] + sp[3];
    const float inv = rsqrtf(ss * (1.f / DM) + EPSV);
    __hip_bfloat16* o_ = out + (long)row * DM;
#pragma unroll
    for (int t = 0; t < 8; ++t) {
        const int j = tid + t * 256;
        o_[j] = __float2bfloat16(v[t] * inv * g[j]);
    }
}

// ---------------- per-head RMSNorm + RoPE (one wave per (s,head)) ----------------
// in:  [s][nheads*128] f32   out: [head*rep+g][s][128] bf16 (rep copies for GQA)
__global__ void qknorm_rope_k(const float* __restrict__ in, const float* __restrict__ ns,
                              const float* __restrict__ cosT, const float* __restrict__ sinT,
                              __hip_bfloat16* __restrict__ out, int nheads, int rep) {
    const int idx = blockIdx.x * 4 + (threadIdx.x >> 6);
    const int lane = threadIdx.x & 63;
    const int s = idx / nheads;
    const int hh = idx - s * nheads;
    const float* r = in + (long)s * (nheads * HDIM) + hh * HDIM;
    const float x1 = r[lane];
    const float x2 = r[lane + 64];
    float ss = wave_sum(x1 * x1 + x2 * x2);
    const float inv = rsqrtf(ss * (1.f / HDIM) + EPSV);
    const float n1 = x1 * inv * ns[lane];
    const float n2 = x2 * inv * ns[lane + 64];
    const float c1 = cosT[s * HDIM + lane],      c2 = cosT[s * HDIM + 64 + lane];
    const float s1 = sinT[s * HDIM + lane],      s2 = sinT[s * HDIM + 64 + lane];
    const __hip_bfloat16 o1 = __float2bfloat16(n1 * c1 - n2 * s1);
    const __hip_bfloat16 o2 = __float2bfloat16(n2 * c2 + n1 * s2);
    for (int g = 0; g < rep; ++g) {
        __hip_bfloat16* w = out + ((long)(hh * rep + g) * SEQ + s) * HDIM;
        w[lane] = o1;
        w[lane + 64] = o2;
    }
}

// ---------------- V transpose+convert (vf [s][kv*128+d] f32 -> vt [qhead][d][s] bf16, GQA-repeated) ----------------
__global__ void vtrans_k(const float* __restrict__ vf, __hip_bfloat16* __restrict__ vt) {
    __shared__ float tile[64][65];
    const int s0 = blockIdx.x * 64, d0 = blockIdx.y * 64, kv = blockIdx.z;
    const int lane = threadIdx.x & 63, part = threadIdx.x >> 6;
    for (int r = part; r < 64; r += 4)
        tile[r][lane] = vf[(long)(s0 + r) * (NKVH * HDIM) + kv * HDIM + d0 + lane];
    __syncthreads();
    for (int r = part; r < 64; r += 4) {
        const __hip_bfloat16 b = __float2bfloat16(tile[lane][r]);
        const long o0 = ((long)(2 * kv) * HDIM + d0 + r) * SEQ + s0 + lane;
        vt[o0] = b;
        vt[o0 + (long)HDIM * SEQ] = b;  // repeated copy for q-head 2*kv+1
    }
}

// ---------------- causal softmax: f32 raw scores -> bf16 probs ----------------
__global__ void softmax_k(const float* __restrict__ sc, __hip_bfloat16* __restrict__ pr) {
    const int i = blockIdx.x;
    const long base = ((long)blockIdx.y * SEQ + i) * SEQ;
    const float* row = sc + base;
    __hip_bfloat16* orow = pr + base;
    const int tid = threadIdx.x;
    const int n = i + 1;
    const float scale = 0.0883883476483184405f;  // 1/sqrt(128)
    float m = -3.0e38f;
    for (int j = tid; j < n; j += 256) m = fmaxf(m, row[j]);
    m = wave_max(m);
    __shared__ float sm[4], ssum[4];
    const int wid = tid >> 6, lane = tid & 63;
    if (lane == 0) sm[wid] = m;
    __syncthreads();
    m = fmaxf(fmaxf(sm[0], sm[1]), fmaxf(sm[2], sm[3])) * scale;
    float s = 0.f;
    for (int j = tid; j < n; j += 256) s += __expf(row[j] * scale - m);
    s = wave_sum(s);
    if (lane == 0) ssum[wid] = s;
    __syncthreads();
    s = ssum[0] + ssum[1] + ssum[2] + ssum[3];
    const float inv = 1.f / s;
    for (int j = tid; j < SEQ; j += 256) {
        const float p = (j < n) ? __expf(row[j] * scale - m) * inv : 0.f;
        orow[j] = __float2bfloat16(p);
    }
}

// ---------------- silu(g)*u elementwise, in place on g ----------------
__global__ void silu_mul_k(__hip_bfloat16* __restrict__ g, const __hip_bfloat16* __restrict__ u) {
    const long i = ((long)blockIdx.x * 256 + threadIdx.x) * 8;
    union { bf16x8 v; __hip_bfloat16 h[8]; } a, b, o;
    a.v = *(const bf16x8*)(g + i);
    b.v = *(const bf16x8*)(u + i);
#pragma unroll
    for (int j = 0; j < 8; ++j) {
        const float xx = __bfloat162float(a.h[j]);
        const float yy = __bfloat162float(b.h[j]);
        const float sv = xx / (1.f + __expf(-xx));
        o.h[j] = __float2bfloat16(sv * yy);
    }
    *(bf16x8*)(g + i) = o.v;
}

// ---------------- bf16 MFMA GEMM: C[M,N] = A[M,K] * B[N,K]^T (+residual) ----------------
// A: bf16 row-major. B: f32 (B_F32=1, converted during staging) or bf16.
// OUT: 0 = f32 C, 1 = bf16 C, 2 = f32 C = Res + acc.
// 2x2 wave grid; wave covers (BM/2)x(BN/2); 16x16x32 MFMA frags.
template <int BM, int BN, int B_F32, int OUT>
__global__ __launch_bounds__(256)
void gemm_bt(const __hip_bfloat16* __restrict__ A, const void* __restrict__ Bv,
             void* __restrict__ Cv, const float* __restrict__ Res,
             int M, int N, int K, int ldC,
             long strideA, long strideB, long strideC, int causal) {
    constexpr int BK = 32;
    constexpr int LA = (BM * BK / 8) / 256;   // 16B chunks per thread (A)
    constexpr int LB = (BN * BK / 8) / 256;
    constexpr int FM = BM / 32;
    constexpr int FN = BN / 32;
    static_assert(LA >= 1 && LB >= 1, "tile too small");

    __shared__ __align__(16) __hip_bfloat16 sA[BM * BK];
    __shared__ __align__(16) __hip_bfloat16 sB[BN * BK];

    const int tid = threadIdx.x;
    const int lane = tid & 63;
    const int wid = tid >> 6;
    const int wr = wid >> 1;
    const int wc = wid & 1;

    const int row0 = blockIdx.y * BM;
    const int col0 = blockIdx.x * BN;
    if (causal && (row0 + BM - 1) < col0) return;  // fully-masked score block

    const int bz = blockIdx.z;
    A += (long)bz * strideA;
    const float* Bf = (const float*)Bv + (long)bz * strideB;
    const __hip_bfloat16* Bb = (const __hip_bfloat16*)Bv + (long)bz * strideB;
    const long cOff = (long)bz * strideC;

    f32x4 acc[FM][FN];
#pragma unroll
    for (int m = 0; m < FM; ++m)
#pragma unroll
        for (int n = 0; n < FN; ++n)
            acc[m][n] = (f32x4){0.f, 0.f, 0.f, 0.f};

    bf16x8 ra[LA];
    bf16x8 rbB[LB];
    float4 rbF0[LB], rbF1[LB];

    auto load_tile = [&](int k0) {
#pragma unroll
        for (int i = 0; i < LA; ++i) {
            const int c = i * 256 + tid;
            ra[i] = *(const bf16x8*)(A + (long)(row0 + (c >> 2)) * K + (k0 + (c & 3) * 8));
        }
#pragma unroll
        for (int i = 0; i < LB; ++i) {
            const int c = i * 256 + tid;
            if constexpr (B_F32) {
                const float* p = Bf + (long)(col0 + (c >> 2)) * K + (k0 + (c & 3) * 8);
                rbF0[i] = *(const float4*)p;
                rbF1[i] = *(const float4*)(p + 4);
            } else {
                rbB[i] = *(const bf16x8*)(Bb + (long)(col0 + (c >> 2)) * K + (k0 + (c & 3) * 8));
            }
        }
    };

    auto store_lds = [&]() {
#pragma unroll
        for (int i = 0; i < LA; ++i)
            *(bf16x8*)&sA[(i * 256 + tid) * 8] = ra[i];
#pragma unroll
        for (int i = 0; i < LB; ++i) {
            if constexpr (B_F32) {
                union { bf16x8 v; __hip_bfloat16 h[8]; } u;
                float t[8];
                *(float4*)&t[0] = rbF0[i];
                *(float4*)&t[4] = rbF1[i];
#pragma unroll
                for (int j = 0; j < 8; ++j) u.h[j] = __float2bfloat16(t[j]);
                *(bf16x8*)&sB[(i * 256 + tid) * 8] = u.v;
            } else {
                *(bf16x8*)&sB[(i * 256 + tid) * 8] = rbB[i];
            }
        }
    };

    const int nk = K / BK;
    load_tile(0);
    for (int kt = 0; kt < nk; ++kt) {
        __syncthreads();           // previous tile fully consumed
        store_lds();               // regs (tile kt) -> LDS
        if (kt + 1 < nk) load_tile((kt + 1) * BK);  // prefetch next tile into regs
        __syncthreads();           // LDS visible
        bf16x8 af[FM], bfg[FN];
#pragma unroll
        for (int m = 0; m < FM; ++m)
            af[m] = *(const bf16x8*)&sA[(wr * (BM / 2) + m * 16 + (lane & 15)) * BK + (lane >> 4) * 8];
#pragma unroll
        for (int n = 0; n < FN; ++n)
            bfg[n] = *(const bf16x8*)&sB[(wc * (BN / 2) + n * 16 + (lane & 15)) * BK + (lane >> 4) * 8];
#pragma unroll
        for (int m = 0; m < FM; ++m)
#pragma unroll
            for (int n = 0; n < FN; ++n)
                acc[m][n] = __builtin_amdgcn_mfma_f32_16x16x32_bf16(af[m], bfg[n], acc[m][n], 0, 0, 0);
    }

    // epilogue: C/D layout col = lane&15, row = (lane>>4)*4 + reg (m89-verified)
#pragma unroll
    for (int m = 0; m < FM; ++m) {
#pragma unroll
        for (int n = 0; n < FN; ++n) {
            const int rb = row0 + wr * (BM / 2) + m * 16 + (lane >> 4) * 4;
            const int cc = col0 + wc * (BN / 2) + n * 16 + (lane & 15);
#pragma unroll
            for (int j = 0; j < 4; ++j) {
                const long idx = cOff + (long)(rb + j) * ldC + cc;
                const float v = acc[m][n][j];
                if constexpr (OUT == 0) ((float*)Cv)[idx] = v;
                else if constexpr (OUT == 1) ((__hip_bfloat16*)Cv)[idx] = __float2bfloat16(v);
                else ((float*)Cv)[idx] = v + Res[idx];
            }
        }
    }
}

// ---------------- host orchestration ----------------
extern "C" void kernel_launch(void* const* d_in, const int* in_sizes, int n_in,
                              void* d_out, int out_size, void* d_ws, size_t ws_size,
                              hipStream_t stream) {
    const int*   ids  = (const int*)d_in[0];
    // d_in[1] = causal mask (implemented analytically)
    const float* cosT = (const float*)d_in[2];
    const float* sinT = (const float*)d_in[3];
    const float* emb  = (const float*)d_in[4];
    const float* q_w  = (const float*)d_in[5];
    const float* k_w  = (const float*)d_in[6];
    const float* v_w  = (const float*)d_in[7];
    const float* o_w  = (const float*)d_in[8];
    const float* qn   = (const float*)d_in[9];
    const float* kn   = (const float*)d_in[10];
    const float* ln1  = (const float*)d_in[11];
    const float* ln2  = (const float*)d_in[12];
    const float* gw   = (const float*)d_in[13];
    const float* uw   = (const float*)d_in[14];
    const float* dw   = (const float*)d_in[15];

    char* W = (char*)d_ws;
    size_t off = 0;
    auto take = [&](size_t nb) { char* p = W + off; off += (nb + 255) & ~(size_t)255; return p; };

    float*          h      = (float*)          take((size_t)SEQ * DM * 4);
    __hip_bfloat16* x      = (__hip_bfloat16*) take((size_t)SEQ * DM * 2);
    float*          qf     = (float*)          take((size_t)SEQ * NHEAD * HDIM * 4);
    float*          kf     = (float*)          take((size_t)SEQ * NKVH * HDIM * 4);
    float*          vf     = (float*)          take((size_t)SEQ * NKVH * HDIM * 4);
    __hip_bfloat16* qb     = (__hip_bfloat16*) take((size_t)NHEAD * SEQ * HDIM * 2);
    __hip_bfloat16* kbr    = (__hip_bfloat16*) take((size_t)NHEAD * SEQ * HDIM * 2);
    __hip_bfloat16* vtr    = (__hip_bfloat16*) take((size_t)NHEAD * HDIM * SEQ * 2);
    __hip_bfloat16* ctx    = (__hip_bfloat16*) take((size_t)SEQ * NHEAD * HDIM * 2);
    float*          scores = (float*)          take((size_t)CHUNK * SEQ * SEQ * 4);
    __hip_bfloat16* probs  = (__hip_bfloat16*) take((size_t)CHUNK * SEQ * SEQ * 2);
    __hip_bfloat16* go     = (__hip_bfloat16*) take((size_t)SEQ * FFN * 2);
    __hip_bfloat16* uo     = (__hip_bfloat16*) take((size_t)SEQ * FFN * 2);
    if (off > ws_size) return;  // workspace too small: fail loudly (output stays zero)

    embed_k<<<SEQ, 256, 0, stream>>>(ids, emb, h);

    for (int l = 0; l < NLAYER; ++l) {
        const float* qwl = q_w + (size_t)l * (NHEAD * HDIM) * DM;
        const float* kwl = k_w + (size_t)l * (NKVH * HDIM) * DM;
        const float* vwl = v_w + (size_t)l * (NKVH * HDIM) * DM;
        const float* owl = o_w + (size_t)l * DM * (NHEAD * HDIM);
        const float* gwl = gw  + (size_t)l * FFN * DM;
        const float* uwl = uw  + (size_t)l * FFN * DM;
        const float* dwl = dw  + (size_t)l * DM * FFN;

        rmsnorm_k<<<SEQ, 256, 0, stream>>>(h, ln1 + l * DM, x);

        gemm_bt<128, 64, 1, 0><<<dim3(NHEAD * HDIM / 64, SEQ / 128, 1), 256, 0, stream>>>(
            x, qwl, qf, nullptr, SEQ, NHEAD * HDIM, DM, NHEAD * HDIM, 0, 0, 0, 0);
        gemm_bt<64, 64, 1, 0><<<dim3(NKVH * HDIM / 64, SEQ / 64, 1), 256, 0, stream>>>(
            x, kwl, kf, nullptr, SEQ, NKVH * HDIM, DM, NKVH * HDIM, 0, 0, 0, 0);
        gemm_bt<64, 64, 1, 0><<<dim3(NKVH * HDIM / 64, SEQ / 64, 1), 256, 0, stream>>>(
            x, vwl, vf, nullptr, SEQ, NKVH * HDIM, DM, NKVH * HDIM, 0, 0, 0, 0);

        qknorm_rope_k<<<SEQ * NHEAD / 4, 256, 0, stream>>>(qf, qn + l * HDIM, cosT, sinT, qb, NHEAD, 1);
        qknorm_rope_k<<<SEQ * NKVH / 4, 256, 0, stream>>>(kf, kn + l * HDIM, cosT, sinT, kbr, NKVH, 2);
        vtrans_k<<<dim3(SEQ / 64, HDIM / 64, NKVH), 256, 0, stream>>>(vf, vtr);

        for (int c = 0; c < NHEAD / CHUNK; ++c) {
            gemm_bt<128, 128, 0, 0><<<dim3(SEQ / 128, SEQ / 128, CHUNK), 256, 0, stream>>>(
                qb + (size_t)c * CHUNK * SEQ * HDIM,
                kbr + (size_t)c * CHUNK * SEQ * HDIM,
                scores, nullptr,
                SEQ, SEQ, HDIM, SEQ,
                (long)SEQ * HDIM, (long)SEQ * HDIM, (long)SEQ * SEQ, 1);
            softmax_k<<<dim3(SEQ, CHUNK), 256, 0, stream>>>(scores, probs);
            gemm_bt<64, 64, 0, 1><<<dim3(HDIM / 64, SEQ / 64, CHUNK), 256, 0, stream>>>(
                probs,
                vtr + (size_t)c * CHUNK * HDIM * SEQ,
                ctx + (size_t)c * CHUNK * HDIM, nullptr,
                SEQ, HDIM, SEQ, NHEAD * HDIM,
                (long)SEQ * SEQ, (long)HDIM * SEQ, (long)HDIM, 0);
        }

        gemm_bt<128, 64, 1, 2><<<dim3(DM / 64, SEQ / 128, 1), 256, 0, stream>>>(
            ctx, owl, h, h, SEQ, DM, NHEAD * HDIM, DM, 0, 0, 0, 0);

        rmsnorm_k<<<SEQ, 256, 0, stream>>>(h, ln2 + l * DM, x);

        gemm_bt<128, 128, 1, 1><<<dim3(FFN / 128, SEQ / 128, 1), 256, 0, stream>>>(
            x, gwl, go, nullptr, SEQ, FFN, DM, FFN, 0, 0, 0, 0);
        gemm_bt<128, 128, 1, 1><<<dim3(FFN / 128, SEQ / 128, 1), 256, 0, stream>>>(
            x, uwl, uo, nullptr, SEQ, FFN, DM, FFN, 0, 0, 0, 0);
        silu_mul_k<<<(SEQ * FFN) / (256 * 8), 256, 0, stream>>>(go, uo);

        gemm_bt<128, 64, 1, 2><<<dim3(DM / 64, SEQ / 128, 1), 256, 0, stream>>>(
            go, dwl, h, h, SEQ, DM, FFN, DM, 0, 0, 0, 0);
    }

    hipMemcpyAsync(d_out, h, (size_t)out_size * sizeof(float), hipMemcpyDeviceToDevice, stream);
}